// Round 5
// baseline (312.899 us; speedup 1.0000x reference)
//
#include <hip/hip_runtime.h>

// Problem constants (match reference file)
#define NROWS    256
#define DCOLS    65536
#define MAXLEN   8192
#define BLKROW   8                    // blocks per row
#define TPB      256
#define V4       8                    // float4/thread: 8*4*256 = 8192 elems/block
#define NWAVE    (TPB / 64)
#define SLOWV4   (DCOLS / 4 / TPB)    // 64 float4/thread in single-block fixup

typedef float f32x4 __attribute__((ext_vector_type(4)));   // nontemporal-builtin-compatible

// Semantics: y[i,j] = x[i,j] if x[i,j]!=0 and rank of j among row i's
// nonzeros < MAXLEN, else 0.  When row_nnz <= MAXLEN this is exactly y = x.
//
// Strategy: speculative coalesced copy y=x + per-block nonzero count.
// Last block of each row (device-scope ticket) checks row nnz; only if
// nnz > MAXLEN (never, for this data: E[nnz]=5243) it redoes the row with
// the ordered rank cutoff, overwriting the speculative copy.
__global__ __launch_bounds__(TPB) void fused_copy_count_fix_kernel(
        const float* __restrict__ x, float* __restrict__ y,
        int* __restrict__ row_nnz, int* __restrict__ row_tkt) {
    const int t    = threadIdx.x;
    const int lane = t & 63;
    const int wave = t >> 6;
    const int row  = blockIdx.x >> 3;          // blockIdx.x / BLKROW
    const size_t base4 = (size_t)blockIdx.x * (TPB * V4);

    const f32x4* __restrict__ x4 = reinterpret_cast<const f32x4*>(x) + base4;
    f32x4* __restrict__ y4       = reinterpret_cast<f32x4*>(y) + base4;

    // ---- Streaming pass: y = x (speculative), count nonzeros ----
    int cnt = 0;
#pragma unroll
    for (int i = 0; i < V4; ++i) {
        f32x4 v = __builtin_nontemporal_load(&x4[i * TPB + t]);
        cnt += (v.x != 0.0f) + (v.y != 0.0f) + (v.z != 0.0f) + (v.w != 0.0f);
        __builtin_nontemporal_store(v, &y4[i * TPB + t]);
    }

    // wave butterfly reduce
#pragma unroll
    for (int off = 32; off; off >>= 1) cnt += __shfl_xor(cnt, off, 64);

    __shared__ int wsum[NWAVE];
    __shared__ int wbase[NWAVE];
    __shared__ int sh_fix;     // 1 iff this block must run the row fixup
    if (lane == 0) wsum[wave] = cnt;
    __syncthreads();           // also drains this block's y stores (vmcnt before s_barrier)

    if (t == 0) {
        int tot = 0;
#pragma unroll
        for (int w = 0; w < NWAVE; ++w) tot += wsum[w];
        __threadfence();                         // release: y stores visible device-wide
        atomicAdd(&row_nnz[row], tot);
        __threadfence();                         // order nnz-add before ticket-add
        int tk = atomicAdd(&row_tkt[row], 1);
        int f = 0;
        if (tk == BLKROW - 1) {                  // last block of this row
            int nnz = atomicAdd(&row_nnz[row], 0);   // all 8 adds globally ordered before
            if (nnz > MAXLEN) f = 1;
        }
        sh_fix = f;
    }
    __syncthreads();
    if (!sh_fix) return;

    // ---- Fixup (nnz > MAXLEN; not taken for this data, kept for correctness).
    //      Ordered rank cutoff over the whole row, this block only.
    //      Happens-after all speculative writes via the ticket release/acquire. ----
    const float4* __restrict__ xc =
        reinterpret_cast<const float4*>(x + (size_t)row * DCOLS) + t * SLOWV4;
    float4* __restrict__ yc =
        reinterpret_cast<float4*>(y + (size_t)row * DCOLS) + t * SLOWV4;

    int ccnt = 0;
    for (int i = 0; i < SLOWV4; ++i) {
        float4 w = xc[i];
        ccnt += (w.x != 0.0f) + (w.y != 0.0f) + (w.z != 0.0f) + (w.w != 0.0f);
    }
    // wave inclusive scan
    int incl = ccnt;
#pragma unroll
    for (int off = 1; off < 64; off <<= 1) {
        int n = __shfl_up(incl, off, 64);
        if (lane >= off) incl += n;
    }
    if (lane == 63) wsum[wave] = incl;
    __syncthreads();
    if (t == 0) {
        int acc = 0;
#pragma unroll
        for (int w = 0; w < NWAVE; ++w) { wbase[w] = acc; acc += wsum[w]; }
    }
    __syncthreads();
    int rank = wbase[wave] + (incl - ccnt);   // exclusive rank at chunk start

    for (int i = 0; i < SLOWV4; ++i) {
        float4 w = xc[i];
        float4 o;
        bool nx = (w.x != 0.0f); o.x = (nx && rank < MAXLEN) ? w.x : 0.0f; rank += nx;
        bool ny = (w.y != 0.0f); o.y = (ny && rank < MAXLEN) ? w.y : 0.0f; rank += ny;
        bool nz = (w.z != 0.0f); o.z = (nz && rank < MAXLEN) ? w.z : 0.0f; rank += nz;
        bool nw = (w.w != 0.0f); o.w = (nw && rank < MAXLEN) ? w.w : 0.0f; rank += nw;
        yc[i] = o;
    }
}

extern "C" void kernel_launch(void* const* d_in, const int* in_sizes, int n_in,
                              void* d_out, int out_size, void* d_ws, size_t ws_size,
                              hipStream_t stream) {
    // d_in[0] = t (unused), d_in[1] = x (256*65536 f32), d_in[2] = embed_table (unused).
    const float* x = (const float*)d_in[1];
    float* y = (float*)d_out;
    int* row_nnz = (int*)d_ws;            // NROWS ints
    int* row_tkt = (int*)d_ws + NROWS;    // NROWS ints

    (void)hipMemsetAsync(d_ws, 0, NROWS * 2 * sizeof(int), stream);  // graph-capturable
    fused_copy_count_fix_kernel<<<NROWS * BLKROW, TPB, 0, stream>>>(x, y, row_nnz, row_tkt);
}

// Round 6
// 171.197 us; speedup vs baseline: 1.8277x; 1.8277x over previous
//
#include <hip/hip_runtime.h>

// Problem constants (match reference file)
#define NROWS    256
#define DCOLS    65536
#define MAXLEN   8192
#define ATPB     256
#define AV4      4                          // float4 per thread in kernel A
#define ABLOCKS  (NROWS * DCOLS / (ATPB * AV4 * 4))   // 4096
#define BLKROW_A (DCOLS / (ATPB * AV4 * 4))           // 16 blocks per row
#define BTPB     1024
#define BV4      (DCOLS / 4 / BTPB)         // 16 float4/thread in fixup
#define NWAVE_B  (BTPB / 64)

typedef float f32x4 __attribute__((ext_vector_type(4)));

// Semantics: y[i,j] = x[i,j] if x[i,j]!=0 and rank of j among row i's
// nonzeros < MAXLEN, else 0.  When row_nnz <= MAXLEN this is exactly y = x.

// ---- Kernel A: pure streaming copy y=x + per-wave nonzero count ----
// No LDS, no barriers, no fences. One device-scope atomicAdd per wave.
__global__ __launch_bounds__(ATPB) void copy_count_kernel(
        const float* __restrict__ x, float* __restrict__ y,
        int* __restrict__ row_nnz) {
    const int t    = threadIdx.x;
    const int lane = t & 63;
    const size_t base4 = (size_t)blockIdx.x * (ATPB * AV4);

    const f32x4* __restrict__ x4 = reinterpret_cast<const f32x4*>(x) + base4;
    f32x4* __restrict__ y4       = reinterpret_cast<f32x4*>(y) + base4;

    int cnt = 0;
#pragma unroll
    for (int i = 0; i < AV4; ++i) {
        f32x4 v = x4[i * ATPB + t];
        cnt += (v.x != 0.0f) + (v.y != 0.0f) + (v.z != 0.0f) + (v.w != 0.0f);
        y4[i * ATPB + t] = v;
    }

    // wave butterfly reduce; one atomic per wave
#pragma unroll
    for (int off = 32; off; off >>= 1) cnt += __shfl_xor(cnt, off, 64);
    if (lane == 0) atomicAdd(&row_nnz[blockIdx.x >> 4], cnt);
}

// ---- Kernel B: per-row check; ordered rank cutoff only if nnz > MAXLEN ----
// (never taken for this data: E[nnz]=5243, MAXLEN=8192; kept for correctness)
__global__ __launch_bounds__(BTPB) void fixup_kernel(
        const float* __restrict__ x, float* __restrict__ y,
        const int* __restrict__ row_nnz) {
    const int row = blockIdx.x;
    const int nnz = row_nnz[row];      // visible: kernel-boundary ordering
    if (nnz <= MAXLEN) return;         // y == x already written by kernel A

    const int t    = threadIdx.x;
    const int lane = t & 63;
    const int wave = t >> 6;

    const float4* __restrict__ xc =
        reinterpret_cast<const float4*>(x + (size_t)row * DCOLS) + t * BV4;
    float4* __restrict__ yc =
        reinterpret_cast<float4*>(y + (size_t)row * DCOLS) + t * BV4;

    int ccnt = 0;
#pragma unroll
    for (int i = 0; i < BV4; ++i) {
        float4 w = xc[i];
        ccnt += (w.x != 0.0f) + (w.y != 0.0f) + (w.z != 0.0f) + (w.w != 0.0f);
    }
    // wave inclusive scan
    int incl = ccnt;
#pragma unroll
    for (int off = 1; off < 64; off <<= 1) {
        int n = __shfl_up(incl, off, 64);
        if (lane >= off) incl += n;
    }
    __shared__ int wsum[NWAVE_B];
    __shared__ int wbase[NWAVE_B];
    if (lane == 63) wsum[wave] = incl;
    __syncthreads();
    if (t == 0) {
        int acc = 0;
#pragma unroll
        for (int w = 0; w < NWAVE_B; ++w) { wbase[w] = acc; acc += wsum[w]; }
    }
    __syncthreads();
    int rank = wbase[wave] + (incl - ccnt);   // exclusive rank at chunk start

#pragma unroll
    for (int i = 0; i < BV4; ++i) {
        float4 w = xc[i];
        float4 o;
        bool nx = (w.x != 0.0f); o.x = (nx && rank < MAXLEN) ? w.x : 0.0f; rank += nx;
        bool ny = (w.y != 0.0f); o.y = (ny && rank < MAXLEN) ? w.y : 0.0f; rank += ny;
        bool nz = (w.z != 0.0f); o.z = (nz && rank < MAXLEN) ? w.z : 0.0f; rank += nz;
        bool nw = (w.w != 0.0f); o.w = (nw && rank < MAXLEN) ? w.w : 0.0f; rank += nw;
        yc[i] = o;
    }
}

extern "C" void kernel_launch(void* const* d_in, const int* in_sizes, int n_in,
                              void* d_out, int out_size, void* d_ws, size_t ws_size,
                              hipStream_t stream) {
    // d_in[0] = t (unused), d_in[1] = x (256*65536 f32), d_in[2] = embed_table (unused).
    const float* x = (const float*)d_in[1];
    float* y = (float*)d_out;
    int* row_nnz = (int*)d_ws;   // NROWS ints (ws poisoned 0xAA -> must zero)

    (void)hipMemsetAsync(row_nnz, 0, NROWS * sizeof(int), stream);
    copy_count_kernel<<<ABLOCKS, ATPB, 0, stream>>>(x, y, row_nnz);
    fixup_kernel<<<NROWS, BTPB, 0, stream>>>(x, y, row_nnz);
}

// Round 7
// 139.913 us; speedup vs baseline: 2.2364x; 1.2236x over previous
//
#include <hip/hip_runtime.h>

// Problem constants (match reference file)
#define NROWS   256
#define DCOLS   65536
#define MAXLEN  8192
#define TPB     1024
#define V4      (DCOLS / 4 / TPB)    // 16 float4 per thread
#define NWAVE   (TPB / 64)

typedef float f32x4 __attribute__((ext_vector_type(4)));

// Semantics: y[i,j] = x[i,j] if x[i,j]!=0 and rank of j among row i's
// nonzeros < MAXLEN, else 0.  When row_nnz <= MAXLEN this is exactly y = x.
//
// Structure: block = row. Speculative streaming copy (load->store immediately,
// no barrier between them -> behaves like a pure copy kernel), nonzero count
// on the fly. Tail: block reduce of nnz; only if nnz > MAXLEN (never for this
// data, E[nnz]=5243) redo the row with the ordered rank cutoff. Block-internal
// overwrite is safe: __syncthreads drains each wave's stores (vmcnt) first.
__global__ __launch_bounds__(TPB) void condense_roundtrip_kernel(
        const float* __restrict__ x, float* __restrict__ y) {
    const int row  = blockIdx.x;
    const int t    = threadIdx.x;
    const int lane = t & 63;
    const int wave = t >> 6;

    const f32x4* __restrict__ x4 =
        reinterpret_cast<const f32x4*>(x + (size_t)row * DCOLS);
    f32x4* __restrict__ y4 =
        reinterpret_cast<f32x4*>(y + (size_t)row * DCOLS);

    // ---- Speculative streaming copy + count (coalesced, no barriers) ----
    int cnt = 0;
#pragma unroll
    for (int i = 0; i < V4; ++i) {
        f32x4 v = x4[i * TPB + t];
        cnt += (v.x != 0.0f) + (v.y != 0.0f) + (v.z != 0.0f) + (v.w != 0.0f);
        y4[i * TPB + t] = v;
    }

    // ---- Tail: row nnz (wave butterfly + tiny LDS reduce) ----
#pragma unroll
    for (int off = 32; off; off >>= 1) cnt += __shfl_xor(cnt, off, 64);

    __shared__ int wsum[NWAVE];
    __shared__ int wbase[NWAVE];
    __shared__ int sh_fix;
    if (lane == 0) wsum[wave] = cnt;
    __syncthreads();                  // also drains this wave's y stores
    if (t == 0) {
        int acc = 0;
#pragma unroll
        for (int w = 0; w < NWAVE; ++w) acc += wsum[w];
        sh_fix = (acc > MAXLEN);
    }
    __syncthreads();
    if (!sh_fix) return;              // y == x is already correct

    // ---- Fixup (nnz > MAXLEN; kept for general correctness, row is L2/L3-hot).
    //      Ordered rank cutoff over contiguous per-thread chunks. ----
    const float4* __restrict__ xc =
        reinterpret_cast<const float4*>(x + (size_t)row * DCOLS) + t * V4;
    float4* __restrict__ yc =
        reinterpret_cast<float4*>(y + (size_t)row * DCOLS) + t * V4;

    int ccnt = 0;
#pragma unroll
    for (int i = 0; i < V4; ++i) {
        float4 w = xc[i];
        ccnt += (w.x != 0.0f) + (w.y != 0.0f) + (w.z != 0.0f) + (w.w != 0.0f);
    }
    // wave inclusive scan
    int incl = ccnt;
#pragma unroll
    for (int off = 1; off < 64; off <<= 1) {
        int n = __shfl_up(incl, off, 64);
        if (lane >= off) incl += n;
    }
    if (lane == 63) wsum[wave] = incl;
    __syncthreads();
    if (t == 0) {
        int acc = 0;
#pragma unroll
        for (int w = 0; w < NWAVE; ++w) { wbase[w] = acc; acc += wsum[w]; }
    }
    __syncthreads();
    int rank = wbase[wave] + (incl - ccnt);   // exclusive rank at chunk start

#pragma unroll
    for (int i = 0; i < V4; ++i) {
        float4 w = xc[i];
        float4 o;
        bool nx = (w.x != 0.0f); o.x = (nx && rank < MAXLEN) ? w.x : 0.0f; rank += nx;
        bool ny = (w.y != 0.0f); o.y = (ny && rank < MAXLEN) ? w.y : 0.0f; rank += ny;
        bool nz = (w.z != 0.0f); o.z = (nz && rank < MAXLEN) ? w.z : 0.0f; rank += nz;
        bool nw = (w.w != 0.0f); o.w = (nw && rank < MAXLEN) ? w.w : 0.0f; rank += nw;
        yc[i] = o;
    }
}

extern "C" void kernel_launch(void* const* d_in, const int* in_sizes, int n_in,
                              void* d_out, int out_size, void* d_ws, size_t ws_size,
                              hipStream_t stream) {
    // d_in[0] = t (unused), d_in[1] = x (256*65536 f32), d_in[2] = embed_table (unused).
    const float* x = (const float*)d_in[1];
    float* y = (float*)d_out;
    condense_roundtrip_kernel<<<NROWS, TPB, 0, stream>>>(x, y);
}